// Round 2
// baseline (2015.603 us; speedup 1.0000x reference)
//
#include <hip/hip_runtime.h>

#define DIMB 64
#define DIMC 16
#define DIMLM 40
#define DIMLE 32
#define DIMD 768
#define DIMR 2048
#define DIMP 49
#define NOBJ 4
#define BC (DIMB * DIMC)

// ---------------- reduction helpers (block = 256 threads = 4 waves) ----------------
__device__ __forceinline__ float warpSum(float v) {
  v += __shfl_down(v, 32); v += __shfl_down(v, 16); v += __shfl_down(v, 8);
  v += __shfl_down(v, 4);  v += __shfl_down(v, 2);  v += __shfl_down(v, 1);
  return v;
}

__device__ __forceinline__ float blockSum256(float v, float* buf) {
  v = warpSum(v);
  int lane = threadIdx.x & 63, wid = threadIdx.x >> 6;
  if (lane == 0) buf[wid] = v;
  __syncthreads();
  float s = buf[0] + buf[1] + buf[2] + buf[3];
  __syncthreads();
  return s;
}

// ---------------- span mean over [start,end] ----------------
__global__ void k_span(const float* __restrict__ mtf, const int* __restrict__ st,
                       const int* __restrict__ en, float* __restrict__ outp) {
  int b = blockIdx.x;
  int s = st[b], e = en[b];
  float cnt = 0.0f;
  for (int p = 0; p < DIMLM; ++p) cnt += (p >= s && p <= e) ? 1.0f : 0.0f;
  float den = fmaxf(cnt, 1e-9f);
  for (int d = threadIdx.x; d < DIMD; d += 256) {
    float acc = 0.0f;
    for (int p = s; p <= e && p < DIMLM; ++p)
      acc += mtf[((size_t)b * DIMLM + p) * DIMD + d];
    outp[b * DIMD + d] = acc / den;
  }
}

// ---------------- entity text masked mean over LE (float4 loads) ----------------
__global__ void k_entrep(const float* __restrict__ etf, const int* __restrict__ etm,
                         float* __restrict__ outp) {
  int bc = blockIdx.x;
  const float4* f = (const float4*)(etf + (size_t)bc * DIMLE * DIMD);
  const int* mk = etm + bc * DIMLE;
  float cnt = 0.0f;
  for (int l = 0; l < DIMLE; ++l) cnt += (float)mk[l];
  float rden = 1.0f / fmaxf(cnt, 1e-9f);
  // D/4 = 192 float4 per row
  for (int d4 = threadIdx.x; d4 < DIMD / 4; d4 += 256) {
    float sx = 0, sy = 0, sz = 0, sw = 0;
    for (int l = 0; l < DIMLE; ++l) {
      float m = (float)mk[l];
      float4 v = f[(size_t)l * (DIMD / 4) + d4];
      sx += v.x * m; sy += v.y * m; sz += v.z * m; sw += v.w * m;
    }
    float4 o = { sx * rden, sy * rden, sz * rden, sw * rden };
    ((float4*)(outp + (size_t)bc * DIMD))[d4] = o;
  }
}

// ---------------- mean over P for [rows, P, R] (float4 loads) ----------------
__global__ void k_pmean(const float* __restrict__ in, float* __restrict__ outp, int np) {
  int row = blockIdx.y;
  int r4 = blockIdx.x * 256 + threadIdx.x;       // float4 index, R/4 = 512 per row
  const float4* p = (const float4*)(in + (size_t)row * np * DIMR) + r4;
  float sx = 0, sy = 0, sz = 0, sw = 0;
  for (int i = 0; i < np; ++i) {
    float4 v = p[(size_t)i * (DIMR / 4)];
    sx += v.x; sy += v.y; sz += v.z; sw += v.w;
  }
  float rn = 1.0f / (float)np;
  float4 o = { sx * rn, sy * rn, sz * rn, sw * rn };
  ((float4*)(outp + (size_t)row * DIMR))[r4] = o;
}

// ---------------- cos(span, entity_text_feature[:,:,0,:]) ----------------
__global__ void k_mtet(const float* __restrict__ span, const float* __restrict__ etf,
                       float* __restrict__ e0) {
  __shared__ float buf[4];
  int bc = blockIdx.x, b = bc >> 4;
  const float* x = span + b * DIMD;
  const float* y = etf + (size_t)bc * DIMLE * DIMD;  // LE index 0
  float dot = 0, nx = 0, ny = 0;
  for (int d = threadIdx.x; d < DIMD; d += 256) {
    float xv = x[d], yv = y[d];
    dot += xv * yv; nx += xv * xv; ny += yv * yv;
  }
  dot = blockSum256(dot, buf);
  nx = blockSum256(nx, buf);
  ny = blockSum256(ny, buf);
  if (threadIdx.x == 0) e0[bc] = dot / fmaxf(sqrtf(nx) * sqrtf(ny), 1e-8f);
}

// ---------------- scalar edge init: e1 = mtei/100, e2 = miet/100 ----------------
__global__ void k_einit(const float* __restrict__ mtei, const float* __restrict__ miet,
                        float* __restrict__ e1, float* __restrict__ e2) {
  int i = blockIdx.x * 256 + threadIdx.x;
  if (i < BC) { e1[i] = mtei[i] * 0.01f; e2[i] = miet[i] * 0.01f; }
}

// ---------------- object pairwise cosine, score-weighted mean ----------------
__global__ void k_miei(const float* __restrict__ mof, const float* __restrict__ eof,
                       const float* __restrict__ mos, const float* __restrict__ eos,
                       float* __restrict__ e3) {
  __shared__ float red[24][4];
  int bc = blockIdx.x, b = bc >> 4;
  const float* mop = mof + (size_t)b * NOBJ * DIMR;
  const float* eop = eof + (size_t)bc * NOBJ * DIMR;
  float dots[16] = {}; float nm2[4] = {}; float ne2[4] = {};
  for (int r = threadIdx.x; r < DIMR; r += 256) {
    float mv[4], ev[4];
#pragma unroll
    for (int m = 0; m < 4; ++m) mv[m] = mop[(size_t)m * DIMR + r];
#pragma unroll
    for (int n = 0; n < 4; ++n) ev[n] = eop[(size_t)n * DIMR + r];
#pragma unroll
    for (int m = 0; m < 4; ++m) {
      nm2[m] += mv[m] * mv[m];
#pragma unroll
      for (int n = 0; n < 4; ++n) dots[m * 4 + n] += mv[m] * ev[n];
    }
#pragma unroll
    for (int n = 0; n < 4; ++n) ne2[n] += ev[n] * ev[n];
  }
  int lane = threadIdx.x & 63, wid = threadIdx.x >> 6;
#pragma unroll
  for (int i = 0; i < 24; ++i) {
    float v = (i < 16) ? dots[i] : (i < 20 ? nm2[i - 16] : ne2[i - 20]);
    v = warpSum(v);
    if (lane == 0) red[i][wid] = v;
  }
  __syncthreads();
  if (threadIdx.x == 0) {
    float dsum[16], nmv[4], nev[4];
    for (int i = 0; i < 16; ++i) dsum[i] = red[i][0] + red[i][1] + red[i][2] + red[i][3];
    for (int m = 0; m < 4; ++m)
      nmv[m] = sqrtf(red[16 + m][0] + red[16 + m][1] + red[16 + m][2] + red[16 + m][3]);
    for (int n = 0; n < 4; ++n)
      nev[n] = sqrtf(red[20 + n][0] + red[20 + n][1] + red[20 + n][2] + red[20 + n][3]);
    float num = 0, den = 0;
    for (int m = 0; m < 4; ++m)
      for (int n = 0; n < 4; ++n) {
        float sim = dsum[m * 4 + n] / fmaxf(nmv[m] * nev[n], 1e-8f);
        float sc = mos[b * 4 + m] * eos[bc * 4 + n];
        num += sim * sc; den += sc;
      }
    e3[bc] = num / (den + 1e-9f);
  }
}

// ---------------- f32 GEMM: C[M,768] = A[M,K] @ W[K,768] + bias ----------------
__global__ __launch_bounds__(256) void k_gemm(const float* __restrict__ A,
                                              const float* __restrict__ W,
                                              const float* __restrict__ bias,
                                              float* __restrict__ Cout,
                                              int Mrows, int K) {
  __shared__ float As[64][17];
  __shared__ float Ws[16][64];
  const int tid = threadIdx.x;
  const int tx = tid & 15, ty = tid >> 4;
  const int n0 = blockIdx.x * 64, m0 = blockIdx.y * 64;
  float acc[4][4] = {};
  for (int k0 = 0; k0 < K; k0 += 16) {
#pragma unroll
    for (int i = 0; i < 4; ++i) {
      int e = tid + i * 256;
      int mm = e >> 4, kk = e & 15;
      As[mm][kk] = A[(size_t)(m0 + mm) * K + k0 + kk];
    }
#pragma unroll
    for (int i = 0; i < 4; ++i) {
      int e = tid + i * 256;
      int kk = e >> 6, nn = e & 63;
      Ws[kk][nn] = W[(size_t)(k0 + kk) * DIMD + n0 + nn];
    }
    __syncthreads();
#pragma unroll
    for (int k = 0; k < 16; ++k) {
      float a[4], bb[4];
#pragma unroll
      for (int i = 0; i < 4; ++i) a[i] = As[ty * 4 + i][k];
#pragma unroll
      for (int j = 0; j < 4; ++j) bb[j] = Ws[k][tx * 4 + j];
#pragma unroll
      for (int i = 0; i < 4; ++i)
#pragma unroll
        for (int j = 0; j < 4; ++j) acc[i][j] = fmaf(a[i], bb[j], acc[i][j]);
    }
    __syncthreads();
  }
#pragma unroll
  for (int i = 0; i < 4; ++i) {
    int mm = m0 + ty * 4 + i;
#pragma unroll
    for (int j = 0; j < 4; ++j) {
      int nn = n0 + tx * 4 + j;
      Cout[(size_t)mm * DIMD + nn] = acc[i][j] + bias[nn];
    }
  }
}

// ---------------- vertex aggregation, mention side (s0, s1) ----------------
__global__ void k_agg_m(const float* __restrict__ v0, const float* __restrict__ v1,
                        const float* __restrict__ v2, const float* __restrict__ v3,
                        const float* __restrict__ e, float* __restrict__ s0,
                        float* __restrict__ s1) {
  int b = blockIdx.x;
  for (int d = threadIdx.x; d < DIMD; d += 256) {
    float a0 = 0, a1 = 0;
    for (int c = 0; c < DIMC; ++c) {
      int bc = b * DIMC + c;
      float x2 = v2[(size_t)bc * DIMD + d], x3 = v3[(size_t)bc * DIMD + d];
      a0 += e[bc] * x2 + e[BC + bc] * x3;
      a1 += e[2 * BC + bc] * x2 + e[3 * BC + bc] * x3;
    }
    s0[b * DIMD + d] = v0[b * DIMD + d] + a0 * (1.0f / DIMC);
    s1[b * DIMD + d] = v1[b * DIMD + d] + a1 * (1.0f / DIMC);
  }
}

// ---------------- vertex aggregation, entity side (s2, s3) ----------------
__global__ void k_agg_e(const float* __restrict__ v0, const float* __restrict__ v1,
                        const float* __restrict__ v2, const float* __restrict__ v3,
                        const float* __restrict__ e, float* __restrict__ s2,
                        float* __restrict__ s3) {
  size_t i = (size_t)blockIdx.x * 256 + threadIdx.x;
  int d = (int)(i % DIMD);
  int bc = (int)(i / DIMD);
  int b = bc >> 4;
  float e0 = e[bc], e1 = e[BC + bc], e2v = e[2 * BC + bc], e3v = e[3 * BC + bc];
  float x0 = v0[b * DIMD + d], x1 = v1[b * DIMD + d];
  s2[i] = v2[i] + e0 * x0 + e2v * x1;
  s3[i] = v3[i] + e1 * x0 + e3v * x1;
}

// ---------------- LayerNorm + ReLU (in-place, one row per block) ----------------
__global__ void k_ln_relu(float* __restrict__ x, const float* __restrict__ g,
                          const float* __restrict__ bb) {
  __shared__ float buf[4];
  float* xr = x + (size_t)blockIdx.x * DIMD;
  float v[3];
  float s = 0.0f;
#pragma unroll
  for (int i = 0; i < 3; ++i) { v[i] = xr[threadIdx.x + i * 256]; s += v[i]; }
  float mu = blockSum256(s, buf) / (float)DIMD;
  float q = 0.0f;
#pragma unroll
  for (int i = 0; i < 3; ++i) { float d = v[i] - mu; q += d * d; }
  float var = blockSum256(q, buf) / (float)DIMD;
  float inv = 1.0f / sqrtf(var + 1e-5f);
#pragma unroll
  for (int i = 0; i < 3; ++i) {
    int d = threadIdx.x + i * 256;
    float y = (v[i] - mu) * inv * g[d] + bb[d];
    xr[d] = fmaxf(y, 0.0f);
  }
}

// ---------------- edge update ----------------
__global__ void k_edge_upd(const float* __restrict__ fu0, const float* __restrict__ fu1,
                           const float* __restrict__ fv2, const float* __restrict__ fv3,
                           const float* __restrict__ eold, float* __restrict__ enew) {
  __shared__ float buf[4];
  int bc = blockIdx.x, b = bc >> 4;
  float d02 = 0, d03 = 0, d12 = 0, d13 = 0;
  for (int d = threadIdx.x; d < DIMD; d += 256) {
    float u0 = fu0[b * DIMD + d], u1 = fu1[b * DIMD + d];
    float w2 = fv2[(size_t)bc * DIMD + d], w3 = fv3[(size_t)bc * DIMD + d];
    d02 += u0 * w2; d03 += u0 * w3; d12 += u1 * w2; d13 += u1 * w3;
  }
  d02 = blockSum256(d02, buf);
  d03 = blockSum256(d03, buf);
  d12 = blockSum256(d12, buf);
  d13 = blockSum256(d13, buf);
  if (threadIdx.x == 0) {
    enew[bc]           = fmaxf(d02 / (float)DIMD + eold[bc], 0.0f);
    enew[BC + bc]      = fmaxf(d03 / (float)DIMD + eold[BC + bc], 0.0f);
    enew[2 * BC + bc]  = fmaxf(d12 / (float)DIMD + eold[2 * BC + bc], 0.0f);
    enew[3 * BC + bc]  = fmaxf(d13 / (float)DIMD + eold[3 * BC + bc], 0.0f);
  }
}

// ---------------- final cosine ----------------
__global__ void k_out(const float* __restrict__ nv0, const float* __restrict__ nv2,
                      float* __restrict__ outp) {
  __shared__ float buf[4];
  int bc = blockIdx.x, b = bc >> 4;
  float dot = 0, n0 = 0, n2 = 0;
  for (int d = threadIdx.x; d < DIMD; d += 256) {
    float x = nv0[b * DIMD + d], y = nv2[(size_t)bc * DIMD + d];
    dot += x * y; n0 += x * x; n2 += y * y;
  }
  dot = blockSum256(dot, buf);
  n0 = blockSum256(n0, buf);
  n2 = blockSum256(n2, buf);
  if (threadIdx.x == 0) outp[bc] = dot / fmaxf(sqrtf(n0) * sqrtf(n2), 1e-8f);
}

extern "C" void kernel_launch(void* const* d_in, const int* in_sizes, int n_in,
                              void* d_out, int out_size, void* d_ws, size_t ws_size,
                              hipStream_t stream) {
  const float* mtf   = (const float*)d_in[0];
  const int*   mstart = (const int*)d_in[2];
  const int*   mend   = (const int*)d_in[3];
  const float* mif   = (const float*)d_in[4];
  const float* mof   = (const float*)d_in[5];
  const float* mos   = (const float*)d_in[6];
  const float* etf   = (const float*)d_in[7];
  const int*   etm   = (const int*)d_in[8];
  const float* eif   = (const float*)d_in[9];
  const float* eof   = (const float*)d_in[10];
  const float* eos   = (const float*)d_in[11];
  const float* miet  = (const float*)d_in[12];
  const float* mtei  = (const float*)d_in[13];
  const float* w_mt = (const float*)d_in[14]; const float* b_mt = (const float*)d_in[15];
  const float* w_et = (const float*)d_in[16]; const float* b_et = (const float*)d_in[17];
  const float* w_mi = (const float*)d_in[18]; const float* b_mi = (const float*)d_in[19];
  const float* w_ei = (const float*)d_in[20]; const float* b_ei = (const float*)d_in[21];
  const float* wh_w = (const float*)d_in[22]; const float* wh_b = (const float*)d_in[23];
  const float* wu_w = (const float*)d_in[24]; const float* wu_b = (const float*)d_in[25];
  const float* wv_w = (const float*)d_in[26]; const float* wv_b = (const float*)d_in[27];
  const float* ln_g = (const float*)d_in[28]; const float* ln_b = (const float*)d_in[29];
  float* out = (float*)d_out;
  float* ws = (float*)d_ws;

  size_t off = 0;
  auto alloc = [&](size_t n) { float* p = ws + off; off += n; return p; };
  float* span   = alloc((size_t)DIMB * DIMD);
  float* entrep = alloc((size_t)BC * DIMD);
  float* mimg   = alloc((size_t)DIMB * DIMR);
  float* eimg   = alloc((size_t)BC * DIMR);
  float* v0[2] = { alloc((size_t)DIMB * DIMD), alloc((size_t)DIMB * DIMD) };
  float* v1[2] = { alloc((size_t)DIMB * DIMD), alloc((size_t)DIMB * DIMD) };
  float* v2[2] = { alloc((size_t)BC * DIMD),   alloc((size_t)BC * DIMD) };
  float* v3[2] = { alloc((size_t)BC * DIMD),   alloc((size_t)BC * DIMD) };
  float* eb[2] = { alloc((size_t)4 * BC),      alloc((size_t)4 * BC) };
  float* s0  = alloc((size_t)DIMB * DIMD);
  float* s1  = alloc((size_t)DIMB * DIMD);
  float* s2  = alloc((size_t)BC * DIMD);
  float* s3  = alloc((size_t)BC * DIMD);
  float* fu0 = alloc((size_t)DIMB * DIMD);
  float* fu1 = alloc((size_t)DIMB * DIMD);
  float* fv2 = alloc((size_t)BC * DIMD);
  float* fv3 = alloc((size_t)BC * DIMD);

  auto gemm = [&](const float* A, const float* W, const float* bias, float* Co,
                  int Mrows, int K) {
    dim3 g(DIMD / 64, Mrows / 64);
    k_gemm<<<g, 256, 0, stream>>>(A, W, bias, Co, Mrows, K);
  };

  // ---- vertex encoder reductions ----
  k_span<<<DIMB, 256, 0, stream>>>(mtf, mstart, mend, span);
  k_entrep<<<BC, 256, 0, stream>>>(etf, etm, entrep);
  k_pmean<<<dim3(DIMR / 4 / 256, DIMB), 256, 0, stream>>>(mif, mimg, DIMP);
  k_pmean<<<dim3(DIMR / 4 / 256, BC), 256, 0, stream>>>(eif, eimg, DIMP);

  // ---- edge encoder ----
  k_mtet<<<BC, 256, 0, stream>>>(span, etf, eb[0]);                      // edge 0
  k_einit<<<(BC + 255) / 256, 256, 0, stream>>>(mtei, miet, eb[0] + BC,  // edge 1
                                                eb[0] + 2 * BC);         // edge 2
  k_miei<<<BC, 256, 0, stream>>>(mof, eof, mos, eos, eb[0] + 3 * BC);    // edge 3

  // ---- vertex projections ----
  gemm(span,   w_mt, b_mt, v0[0], DIMB, DIMD);
  gemm(entrep, w_et, b_et, v2[0], BC,   DIMD);
  gemm(mimg,   w_mi, b_mi, v1[0], DIMB, DIMR);
  gemm(eimg,   w_ei, b_ei, v3[0], BC,   DIMR);

  // ---- GCN layers ----
  int cur = 0;
  for (int l = 0; l < 2; ++l) {
    int nxt = cur ^ 1;
    const float* wh = wh_w + (size_t)l * DIMD * DIMD; const float* bh = wh_b + l * DIMD;
    const float* wu = wu_w + (size_t)l * DIMD * DIMD; const float* bu = wu_b + l * DIMD;
    const float* wv = wv_w + (size_t)l * DIMD * DIMD; const float* bv = wv_b + l * DIMD;
    const float* g  = ln_g + l * DIMD;               const float* bl = ln_b + l * DIMD;

    k_agg_m<<<DIMB, 256, 0, stream>>>(v0[cur], v1[cur], v2[cur], v3[cur], eb[cur], s0, s1);
    k_agg_e<<<(BC * DIMD) / 256, 256, 0, stream>>>(v0[cur], v1[cur], v2[cur], v3[cur],
                                                   eb[cur], s2, s3);
    gemm(s0, wh, bh, v0[nxt], DIMB, DIMD);
    gemm(s1, wh, bh, v1[nxt], DIMB, DIMD);
    gemm(s2, wh, bh, v2[nxt], BC, DIMD);
    gemm(s3, wh, bh, v3[nxt], BC, DIMD);
    k_ln_relu<<<DIMB, 256, 0, stream>>>(v0[nxt], g, bl);
    k_ln_relu<<<DIMB, 256, 0, stream>>>(v1[nxt], g, bl);
    k_ln_relu<<<BC, 256, 0, stream>>>(v2[nxt], g, bl);
    k_ln_relu<<<BC, 256, 0, stream>>>(v3[nxt], g, bl);

    gemm(v0[cur], wu, bu, fu0, DIMB, DIMD);
    gemm(v1[cur], wu, bu, fu1, DIMB, DIMD);
    gemm(v2[cur], wv, bv, fv2, BC, DIMD);
    gemm(v3[cur], wv, bv, fv3, BC, DIMD);
    k_edge_upd<<<BC, 256, 0, stream>>>(fu0, fu1, fv2, fv3, eb[cur], eb[nxt]);
    cur = nxt;
  }

  // ---- output cosine ----
  k_out<<<BC, 256, 0, stream>>>(v0[cur], v2[cur], out);
}

// Round 3
// 1140.351 us; speedup vs baseline: 1.7675x; 1.7675x over previous
//
#include <hip/hip_runtime.h>

#define DIMB 64
#define DIMC 16
#define DIMLM 40
#define DIMLE 32
#define DIMD 768
#define DIMR 2048
#define DIMP 49
#define BC (DIMB * DIMC)

typedef __attribute__((ext_vector_type(8))) short short8;
typedef __attribute__((ext_vector_type(4))) float f32x4;

// ---------------- reduction helpers ----------------
__device__ __forceinline__ float warpSum(float v) {
  v += __shfl_down(v, 32); v += __shfl_down(v, 16); v += __shfl_down(v, 8);
  v += __shfl_down(v, 4);  v += __shfl_down(v, 2);  v += __shfl_down(v, 1);
  return v;
}

__device__ __forceinline__ float blockSum256(float v, float* buf) {
  v = warpSum(v);
  int lane = threadIdx.x & 63, wid = threadIdx.x >> 6;
  if (lane == 0) buf[wid] = v;
  __syncthreads();
  float s = buf[0] + buf[1] + buf[2] + buf[3];
  __syncthreads();
  return s;
}

// split f32 -> bf16 hi (truncate) + bf16 lo (RNE of residual)
__device__ __forceinline__ void splitf(float x, unsigned short& h, unsigned short& l) {
  unsigned bx = __float_as_uint(x);
  h = (unsigned short)(bx >> 16);
  float lo = x - __uint_as_float(bx & 0xffff0000u);
  unsigned bl = __float_as_uint(lo);
  l = (unsigned short)((bl + 0x7fffu + ((bl >> 16) & 1u)) >> 16);
}

// ---------------- span mean ----------------
__global__ void k_span(const float* __restrict__ mtf, const int* __restrict__ st,
                       const int* __restrict__ en, float* __restrict__ outp) {
  int b = blockIdx.x;
  int s = st[b], e = en[b];
  float cnt = 0.0f;
  for (int p = 0; p < DIMLM; ++p) cnt += (p >= s && p <= e) ? 1.0f : 0.0f;
  float den = fmaxf(cnt, 1e-9f);
  for (int d = threadIdx.x; d < DIMD; d += 256) {
    float acc = 0.0f;
    for (int p = s; p <= e && p < DIMLM; ++p)
      acc += mtf[((size_t)b * DIMLM + p) * DIMD + d];
    outp[b * DIMD + d] = acc / den;
  }
}

// ---------------- entity text masked mean (float4) ----------------
__global__ void k_entrep(const float* __restrict__ etf, const int* __restrict__ etm,
                         float* __restrict__ outp) {
  int bc = blockIdx.x;
  const float4* f = (const float4*)(etf + (size_t)bc * DIMLE * DIMD);
  const int* mk = etm + bc * DIMLE;
  float cnt = 0.0f;
  for (int l = 0; l < DIMLE; ++l) cnt += (float)mk[l];
  float rden = 1.0f / fmaxf(cnt, 1e-9f);
  for (int d4 = threadIdx.x; d4 < DIMD / 4; d4 += 256) {
    float sx = 0, sy = 0, sz = 0, sw = 0;
    for (int l = 0; l < DIMLE; ++l) {
      float m = (float)mk[l];
      float4 v = f[(size_t)l * (DIMD / 4) + d4];
      sx += v.x * m; sy += v.y * m; sz += v.z * m; sw += v.w * m;
    }
    float4 o = { sx * rden, sy * rden, sz * rden, sw * rden };
    ((float4*)(outp + (size_t)bc * DIMD))[d4] = o;
  }
}

// ---------------- mean over P (float4) ----------------
__global__ void k_pmean(const float* __restrict__ in, float* __restrict__ outp, int np) {
  int row = blockIdx.y;
  int r4 = blockIdx.x * 256 + threadIdx.x;
  const float4* p = (const float4*)(in + (size_t)row * np * DIMR) + r4;
  float sx = 0, sy = 0, sz = 0, sw = 0;
  for (int i = 0; i < np; ++i) {
    float4 v = p[(size_t)i * (DIMR / 4)];
    sx += v.x; sy += v.y; sz += v.z; sw += v.w;
  }
  float rn = 1.0f / (float)np;
  float4 o = { sx * rn, sy * rn, sz * rn, sw * rn };
  ((float4*)(outp + (size_t)row * DIMR))[r4] = o;
}

// ---------------- cos(span, etf[:,:,0]) ----------------
__global__ void k_mtet(const float* __restrict__ span, const float* __restrict__ etf,
                       float* __restrict__ e0) {
  __shared__ float buf[4];
  int bc = blockIdx.x, b = bc >> 4;
  const float* x = span + b * DIMD;
  const float* y = etf + (size_t)bc * DIMLE * DIMD;
  float dot = 0, nx = 0, ny = 0;
  for (int d = threadIdx.x; d < DIMD; d += 256) {
    float xv = x[d], yv = y[d];
    dot += xv * yv; nx += xv * xv; ny += yv * yv;
  }
  dot = blockSum256(dot, buf);
  nx = blockSum256(nx, buf);
  ny = blockSum256(ny, buf);
  if (threadIdx.x == 0) e0[bc] = dot / fmaxf(sqrtf(nx) * sqrtf(ny), 1e-8f);
}

__global__ void k_einit(const float* __restrict__ mtei, const float* __restrict__ miet,
                        float* __restrict__ e1, float* __restrict__ e2) {
  int i = blockIdx.x * 256 + threadIdx.x;
  if (i < BC) { e1[i] = mtei[i] * 0.01f; e2[i] = miet[i] * 0.01f; }
}

// ---------------- object pairwise cosine ----------------
__global__ void k_miei(const float* __restrict__ mof, const float* __restrict__ eof,
                       const float* __restrict__ mos, const float* __restrict__ eos,
                       float* __restrict__ e3) {
  __shared__ float red[24][4];
  int bc = blockIdx.x, b = bc >> 4;
  const float* mop = mof + (size_t)b * 4 * DIMR;
  const float* eop = eof + (size_t)bc * 4 * DIMR;
  float dots[16] = {}; float nm2[4] = {}; float ne2[4] = {};
  for (int r = threadIdx.x; r < DIMR; r += 256) {
    float mv[4], ev[4];
#pragma unroll
    for (int m = 0; m < 4; ++m) mv[m] = mop[(size_t)m * DIMR + r];
#pragma unroll
    for (int n = 0; n < 4; ++n) ev[n] = eop[(size_t)n * DIMR + r];
#pragma unroll
    for (int m = 0; m < 4; ++m) {
      nm2[m] += mv[m] * mv[m];
#pragma unroll
      for (int n = 0; n < 4; ++n) dots[m * 4 + n] += mv[m] * ev[n];
    }
#pragma unroll
    for (int n = 0; n < 4; ++n) ne2[n] += ev[n] * ev[n];
  }
  int lane = threadIdx.x & 63, wid = threadIdx.x >> 6;
#pragma unroll
  for (int i = 0; i < 24; ++i) {
    float v = (i < 16) ? dots[i] : (i < 20 ? nm2[i - 16] : ne2[i - 20]);
    v = warpSum(v);
    if (lane == 0) red[i][wid] = v;
  }
  __syncthreads();
  if (threadIdx.x == 0) {
    float dsum[16], nmv[4], nev[4];
    for (int i = 0; i < 16; ++i) dsum[i] = red[i][0] + red[i][1] + red[i][2] + red[i][3];
    for (int m = 0; m < 4; ++m)
      nmv[m] = sqrtf(red[16 + m][0] + red[16 + m][1] + red[16 + m][2] + red[16 + m][3]);
    for (int n = 0; n < 4; ++n)
      nev[n] = sqrtf(red[20 + n][0] + red[20 + n][1] + red[20 + n][2] + red[20 + n][3]);
    float num = 0, den = 0;
    for (int m = 0; m < 4; ++m)
      for (int n = 0; n < 4; ++n) {
        float sim = dsum[m * 4 + n] / fmaxf(nmv[m] * nev[n], 1e-8f);
        float sc = mos[b * 4 + m] * eos[bc * 4 + n];
        num += sim * sc; den += sc;
      }
    e3[bc] = num / (den + 1e-9f);
  }
}

// ---------------- weight transpose + bf16 hi/lo split ----------------
struct WDesc { const float* W; unsigned short* Th; unsigned short* Tl; int K; };
struct WDescs { WDesc d[10]; };
__global__ void k_wsplitT(WDescs wd) {
  const WDesc D = wd.d[blockIdx.z];
  int kb = blockIdx.x * 32;
  if (kb >= D.K) return;
  int nb = blockIdx.y * 32;
  __shared__ float t[32][33];
  int c = threadIdx.x & 31, r8 = threadIdx.x >> 5;
#pragma unroll
  for (int i = 0; i < 4; ++i) {
    int kk = r8 + i * 8;
    t[kk][c] = D.W[(size_t)(kb + kk) * DIMD + nb + c];
  }
  __syncthreads();
#pragma unroll
  for (int i = 0; i < 4; ++i) {
    int nn = r8 + i * 8;
    unsigned short h, l;
    splitf(t[c][nn], h, l);
    size_t o = (size_t)(nb + nn) * D.K + kb + c;
    D.Th[o] = h; D.Tl[o] = l;
  }
}

// ---------------- activation bf16 hi/lo split (batched, float4) ----------------
struct ADesc { const float* X; unsigned short* H; unsigned short* L; };
struct ADescs { ADesc d[4]; int cum[5]; int nd; };
__global__ void k_asplit(ADescs ad) {
  int i4 = blockIdx.x * 256 + threadIdx.x;
  for (int z = 0; z < ad.nd; ++z) {
    if (i4 < ad.cum[z + 1]) {
      int off = i4 - ad.cum[z];
      const ADesc D = ad.d[z];
      float4 v = ((const float4*)D.X)[off];
      unsigned short h0, h1, h2, h3, l0, l1, l2, l3;
      splitf(v.x, h0, l0); splitf(v.y, h1, l1);
      splitf(v.z, h2, l2); splitf(v.w, h3, l3);
      uint2 hp, lp;
      hp.x = (unsigned)h0 | ((unsigned)h1 << 16); hp.y = (unsigned)h2 | ((unsigned)h3 << 16);
      lp.x = (unsigned)l0 | ((unsigned)l1 << 16); lp.y = (unsigned)l2 | ((unsigned)l3 << 16);
      ((uint2*)D.H)[off] = hp;
      ((uint2*)D.L)[off] = lp;
      return;
    }
  }
}

// ---------------- split-bf16 MFMA GEMM, batched descriptors ----------------
// C[M,768] = A[M,K] @ W[K,768] + bias ; A,W pre-split to bf16 hi/lo, W transposed [768][K]
#define BMg 128
#define BNg 128
#define BKg 32
#define LDP 40   // padded row stride in ushorts (32 + 8)
struct GDesc {
  const unsigned short *Ah, *Al, *Wh, *Wl;
  const float* bias; float* C; int M, K, mb0;
};
struct GDescs { GDesc d[4]; int nd; };

__global__ __launch_bounds__(256) void k_gemm_mfma(GDescs gd) {
  int bx = blockIdx.x;
  int z = 0;
  while (z + 1 < gd.nd && bx >= gd.d[z + 1].mb0) ++z;
  const GDesc D = gd.d[z];
  const int m0 = (bx - D.mb0) * BMg;
  const int n0 = blockIdx.y * BNg;
  const int K = D.K, M = D.M;

  __shared__ unsigned short sAh[2][BMg * LDP];
  __shared__ unsigned short sAl[2][BMg * LDP];
  __shared__ unsigned short sWh[2][BMg * LDP];
  __shared__ unsigned short sWl[2][BMg * LDP];

  const int tid = threadIdx.x;
  uint4 st[8];

  auto issue = [&](int kt) {
    int k0 = kt * BKg;
#pragma unroll
    for (int i = 0; i < 8; ++i) {
      int u = tid + (i & 1) * 256;   // unit 0..511 per plane
      int r = u >> 2, q = u & 3;
      const unsigned short* src;
      int row;
      if (i < 4) { row = m0 + r; if (row >= M) row = M - 1; src = (i < 2) ? D.Ah : D.Al; }
      else       { row = n0 + r;                            src = (i < 6) ? D.Wh : D.Wl; }
      st[i] = *(const uint4*)(src + (size_t)row * K + k0 + q * 8);
    }
  };
  auto commit = [&](int b) {
#pragma unroll
    for (int i = 0; i < 8; ++i) {
      int u = tid + (i & 1) * 256;
      int r = u >> 2, q = u & 3;
      unsigned short* dst = (i < 2) ? sAh[b] : (i < 4) ? sAl[b] : (i < 6) ? sWh[b] : sWl[b];
      *(uint4*)(dst + r * LDP + q * 8) = st[i];
    }
  };

  f32x4 acc[4][4];
#pragma unroll
  for (int i = 0; i < 4; ++i)
#pragma unroll
    for (int j = 0; j < 4; ++j) acc[i][j] = (f32x4){0.f, 0.f, 0.f, 0.f};

  const int lane = tid & 63, w = tid >> 6;
  const int wr = (w >> 1) * 64, wc = (w & 1) * 64;  // wave tile 64x64 in 2x2 grid
  const int fr = lane & 15, fg = lane >> 4;

  issue(0); commit(0); __syncthreads();
  const int nt = K / BKg;
  for (int t = 0; t < nt; ++t) {
    int b = t & 1;
    if (t + 1 < nt) issue(t + 1);
    short8 ah[4], al[4];
#pragma unroll
    for (int mi = 0; mi < 4; ++mi) {
      int ro = (wr + mi * 16 + fr) * LDP + fg * 8;
      ah[mi] = *(const short8*)(sAh[b] + ro);
      al[mi] = *(const short8*)(sAl[b] + ro);
    }
#pragma unroll
    for (int ni = 0; ni < 4; ++ni) {
      int co = (wc + ni * 16 + fr) * LDP + fg * 8;
      short8 wh8 = *(const short8*)(sWh[b] + co);
      short8 wl8 = *(const short8*)(sWl[b] + co);
#pragma unroll
      for (int mi = 0; mi < 4; ++mi) {
        acc[mi][ni] = __builtin_amdgcn_mfma_f32_16x16x32_bf16(ah[mi], wh8, acc[mi][ni], 0, 0, 0);
        acc[mi][ni] = __builtin_amdgcn_mfma_f32_16x16x32_bf16(ah[mi], wl8, acc[mi][ni], 0, 0, 0);
        acc[mi][ni] = __builtin_amdgcn_mfma_f32_16x16x32_bf16(al[mi], wh8, acc[mi][ni], 0, 0, 0);
      }
    }
    if (t + 1 < nt) commit((t + 1) & 1);
    __syncthreads();
  }

#pragma unroll
  for (int mi = 0; mi < 4; ++mi) {
#pragma unroll
    for (int r = 0; r < 4; ++r) {
      int grow = m0 + wr + mi * 16 + fg * 4 + r;
      if (grow < M) {
#pragma unroll
        for (int ni = 0; ni < 4; ++ni) {
          int gcol = n0 + wc + ni * 16 + fr;
          D.C[(size_t)grow * DIMD + gcol] = acc[mi][ni][r] + D.bias[gcol];
        }
      }
    }
  }
}

// ---------------- vertex aggregation into SCAT ----------------
// V layout: rows [v0(64); v1(64); v2(1024); v3(1024)]
__global__ void k_agg_m(const float* __restrict__ V, const float* __restrict__ e,
                        float* __restrict__ SC) {
  int b = blockIdx.x;
  const float* v0 = V;
  const float* v1 = V + 64 * DIMD;
  const float* v2 = V + 128 * DIMD;
  const float* v3 = V + 1152 * DIMD;
  for (int d = threadIdx.x; d < DIMD; d += 256) {
    float a0 = 0, a1 = 0;
    for (int c = 0; c < DIMC; ++c) {
      int bc = b * DIMC + c;
      float x2 = v2[(size_t)bc * DIMD + d], x3 = v3[(size_t)bc * DIMD + d];
      a0 += e[bc] * x2 + e[BC + bc] * x3;
      a1 += e[2 * BC + bc] * x2 + e[3 * BC + bc] * x3;
    }
    SC[(size_t)b * DIMD + d] = v0[b * DIMD + d] + a0 * (1.0f / DIMC);
    SC[(size_t)(64 + b) * DIMD + d] = v1[b * DIMD + d] + a1 * (1.0f / DIMC);
  }
}

__global__ void k_agg_e(const float* __restrict__ V, const float* __restrict__ e,
                        float* __restrict__ SC) {
  size_t i = (size_t)blockIdx.x * 256 + threadIdx.x;  // over 1024*768
  int d = (int)(i % DIMD);
  int bc = (int)(i / DIMD);
  int b = bc >> 4;
  const float* v0 = V;
  const float* v1 = V + 64 * DIMD;
  const float* v2 = V + 128 * DIMD;
  const float* v3 = V + 1152 * DIMD;
  float e0 = e[bc], e1 = e[BC + bc], e2v = e[2 * BC + bc], e3v = e[3 * BC + bc];
  float x0 = v0[b * DIMD + d], x1 = v1[b * DIMD + d];
  SC[(size_t)128 * DIMD + i] = v2[i] + e0 * x0 + e2v * x1;
  SC[(size_t)1152 * DIMD + i] = v3[i] + e1 * x0 + e3v * x1;
}

// ---------------- LayerNorm + ReLU ----------------
__global__ void k_ln_relu(float* __restrict__ x, const float* __restrict__ g,
                          const float* __restrict__ bb) {
  __shared__ float buf[4];
  float* xr = x + (size_t)blockIdx.x * DIMD;
  float v[3];
  float s = 0.0f;
#pragma unroll
  for (int i = 0; i < 3; ++i) { v[i] = xr[threadIdx.x + i * 256]; s += v[i]; }
  float mu = blockSum256(s, buf) / (float)DIMD;
  float q = 0.0f;
#pragma unroll
  for (int i = 0; i < 3; ++i) { float d = v[i] - mu; q += d * d; }
  float var = blockSum256(q, buf) / (float)DIMD;
  float inv = 1.0f / sqrtf(var + 1e-5f);
#pragma unroll
  for (int i = 0; i < 3; ++i) {
    int d = threadIdx.x + i * 256;
    float y = (v[i] - mu) * inv * g[d] + bb[d];
    xr[d] = fmaxf(y, 0.0f);
  }
}

// ---------------- edge update ----------------
__global__ void k_edge_upd(const float* __restrict__ FU, const float* __restrict__ FV,
                           const float* __restrict__ eold, float* __restrict__ enew) {
  __shared__ float buf[4];
  int bc = blockIdx.x, b = bc >> 4;
  const float* fu0 = FU;
  const float* fu1 = FU + 64 * DIMD;
  const float* fv2 = FV;
  const float* fv3 = FV + 1024 * DIMD;
  float d02 = 0, d03 = 0, d12 = 0, d13 = 0;
  for (int d = threadIdx.x; d < DIMD; d += 256) {
    float u0 = fu0[b * DIMD + d], u1 = fu1[b * DIMD + d];
    float w2 = fv2[(size_t)bc * DIMD + d], w3 = fv3[(size_t)bc * DIMD + d];
    d02 += u0 * w2; d03 += u0 * w3; d12 += u1 * w2; d13 += u1 * w3;
  }
  d02 = blockSum256(d02, buf);
  d03 = blockSum256(d03, buf);
  d12 = blockSum256(d12, buf);
  d13 = blockSum256(d13, buf);
  if (threadIdx.x == 0) {
    enew[bc]          = fmaxf(d02 / (float)DIMD + eold[bc], 0.0f);
    enew[BC + bc]     = fmaxf(d03 / (float)DIMD + eold[BC + bc], 0.0f);
    enew[2 * BC + bc] = fmaxf(d12 / (float)DIMD + eold[2 * BC + bc], 0.0f);
    enew[3 * BC + bc] = fmaxf(d13 / (float)DIMD + eold[3 * BC + bc], 0.0f);
  }
}

// ---------------- final cosine ----------------
__global__ void k_out(const float* __restrict__ V, float* __restrict__ outp) {
  __shared__ float buf[4];
  int bc = blockIdx.x, b = bc >> 4;
  const float* nv0 = V;
  const float* nv2 = V + 128 * DIMD;
  float dot = 0, n0 = 0, n2 = 0;
  for (int d = threadIdx.x; d < DIMD; d += 256) {
    float x = nv0[b * DIMD + d], y = nv2[(size_t)bc * DIMD + d];
    dot += x * y; n0 += x * x; n2 += y * y;
  }
  dot = blockSum256(dot, buf);
  n0 = blockSum256(n0, buf);
  n2 = blockSum256(n2, buf);
  if (threadIdx.x == 0) outp[bc] = dot / fmaxf(sqrtf(n0) * sqrtf(n2), 1e-8f);
}

extern "C" void kernel_launch(void* const* d_in, const int* in_sizes, int n_in,
                              void* d_out, int out_size, void* d_ws, size_t ws_size,
                              hipStream_t stream) {
  const float* mtf    = (const float*)d_in[0];
  const int*   mstart = (const int*)d_in[2];
  const int*   mend   = (const int*)d_in[3];
  const float* mif  = (const float*)d_in[4];
  const float* mof  = (const float*)d_in[5];
  const float* mos  = (const float*)d_in[6];
  const float* etf  = (const float*)d_in[7];
  const int*   etm  = (const int*)d_in[8];
  const float* eif  = (const float*)d_in[9];
  const float* eof  = (const float*)d_in[10];
  const float* eos  = (const float*)d_in[11];
  const float* miet = (const float*)d_in[12];
  const float* mtei = (const float*)d_in[13];
  const float* w_mt = (const float*)d_in[14]; const float* b_mt = (const float*)d_in[15];
  const float* w_et = (const float*)d_in[16]; const float* b_et = (const float*)d_in[17];
  const float* w_mi = (const float*)d_in[18]; const float* b_mi = (const float*)d_in[19];
  const float* w_ei = (const float*)d_in[20]; const float* b_ei = (const float*)d_in[21];
  const float* wh_w = (const float*)d_in[22]; const float* wh_b = (const float*)d_in[23];
  const float* wu_w = (const float*)d_in[24]; const float* wu_b = (const float*)d_in[25];
  const float* wv_w = (const float*)d_in[26]; const float* wv_b = (const float*)d_in[27];
  const float* ln_g = (const float*)d_in[28]; const float* ln_b = (const float*)d_in[29];
  float* out = (float*)d_out;

  // ---------------- workspace layout ----------------
  float* ws = (float*)d_ws;
  size_t off = 0;
  auto alloc = [&](size_t n) { float* p = ws + off; off += n; return p; };
  const size_t NV = 2176;  // [v0(64); v1(64); v2(1024); v3(1024)]
  float* span   = alloc((size_t)DIMB * DIMD);
  float* entrep = alloc((size_t)BC * DIMD);
  float* mimg   = alloc((size_t)DIMB * DIMR);
  float* eimg   = alloc((size_t)BC * DIMR);
  float* V[2]   = { alloc(NV * DIMD), alloc(NV * DIMD) };
  float* SCAT   = alloc(NV * DIMD);
  float* FU     = alloc((size_t)128 * DIMD);
  float* FV     = alloc((size_t)2048 * DIMD);
  float* ebuf[2] = { alloc((size_t)4 * BC), alloc((size_t)4 * BC) };

  unsigned short* us = (unsigned short*)(ws + off);
  size_t uoff = 0;
  auto ualloc = [&](size_t n) { unsigned short* p = us + uoff; uoff += n; return p; };
  unsigned short* sp_h = ualloc(64 * 768);   unsigned short* sp_l = ualloc(64 * 768);
  unsigned short* mi_h = ualloc(64 * 2048);  unsigned short* mi_l = ualloc(64 * 2048);
  unsigned short* en_h = ualloc(1024 * 768); unsigned short* en_l = ualloc(1024 * 768);
  unsigned short* ei_h = ualloc((size_t)1024 * 2048); unsigned short* ei_l = ualloc((size_t)1024 * 2048);
  unsigned short* sc_h = ualloc(NV * 768);   unsigned short* sc_l = ualloc(NV * 768);
  unsigned short* vv_h = ualloc(NV * 768);   unsigned short* vv_l = ualloc(NV * 768);
  unsigned short* wmtT_h = ualloc(768 * 768);  unsigned short* wmtT_l = ualloc(768 * 768);
  unsigned short* wetT_h = ualloc(768 * 768);  unsigned short* wetT_l = ualloc(768 * 768);
  unsigned short* wmiT_h = ualloc((size_t)768 * 2048); unsigned short* wmiT_l = ualloc((size_t)768 * 2048);
  unsigned short* weiT_h = ualloc((size_t)768 * 2048); unsigned short* weiT_l = ualloc((size_t)768 * 2048);
  unsigned short* whT_h[2] = { ualloc(768 * 768), ualloc(768 * 768) };
  unsigned short* whT_l[2] = { ualloc(768 * 768), ualloc(768 * 768) };
  unsigned short* wuT_h[2] = { ualloc(768 * 768), ualloc(768 * 768) };
  unsigned short* wuT_l[2] = { ualloc(768 * 768), ualloc(768 * 768) };
  unsigned short* wvT_h[2] = { ualloc(768 * 768), ualloc(768 * 768) };
  unsigned short* wvT_l[2] = { ualloc(768 * 768), ualloc(768 * 768) };

  // ---------------- stage 1: reductions + edges ----------------
  k_span<<<DIMB, 256, 0, stream>>>(mtf, mstart, mend, span);
  k_entrep<<<BC, 256, 0, stream>>>(etf, etm, entrep);
  k_pmean<<<dim3(DIMR / 4 / 256, DIMB), 256, 0, stream>>>(mif, mimg, DIMP);
  k_pmean<<<dim3(DIMR / 4 / 256, BC), 256, 0, stream>>>(eif, eimg, DIMP);
  k_mtet<<<BC, 256, 0, stream>>>(span, etf, ebuf[0]);
  k_einit<<<(BC + 255) / 256, 256, 0, stream>>>(mtei, miet, ebuf[0] + BC, ebuf[0] + 2 * BC);
  k_miei<<<BC, 256, 0, stream>>>(mof, eof, mos, eos, ebuf[0] + 3 * BC);

  // ---------------- stage 2: weight transpose+split (once) ----------------
  {
    WDescs wd;
    wd.d[0] = { w_mt, wmtT_h, wmtT_l, 768 };
    wd.d[1] = { w_et, wetT_h, wetT_l, 768 };
    wd.d[2] = { w_mi, wmiT_h, wmiT_l, 2048 };
    wd.d[3] = { w_ei, weiT_h, weiT_l, 2048 };
    wd.d[4] = { wh_w,             whT_h[0], whT_l[0], 768 };
    wd.d[5] = { wh_w + 768 * 768, whT_h[1], whT_l[1], 768 };
    wd.d[6] = { wu_w,             wuT_h[0], wuT_l[0], 768 };
    wd.d[7] = { wu_w + 768 * 768, wuT_h[1], wuT_l[1], 768 };
    wd.d[8] = { wv_w,             wvT_h[0], wvT_l[0], 768 };
    wd.d[9] = { wv_w + 768 * 768, wvT_h[1], wvT_l[1], 768 };
    k_wsplitT<<<dim3(2048 / 32, 768 / 32, 10), 256, 0, stream>>>(wd);
  }

  // ---------------- stage 3: split proj inputs ----------------
  {
    ADescs ad;
    ad.nd = 4;
    ad.d[0] = { span,   sp_h, sp_l };
    ad.d[1] = { mimg,   mi_h, mi_l };
    ad.d[2] = { entrep, en_h, en_l };
    ad.d[3] = { eimg,   ei_h, ei_l };
    ad.cum[0] = 0;
    ad.cum[1] = 64 * 768 / 4;
    ad.cum[2] = ad.cum[1] + 64 * 2048 / 4;
    ad.cum[3] = ad.cum[2] + 1024 * 768 / 4;
    ad.cum[4] = ad.cum[3] + 1024 * 2048 / 4;
    k_asplit<<<(ad.cum[4] + 255) / 256, 256, 0, stream>>>(ad);
  }

  // ---------------- stage 4: projection GEMMs (batched) ----------------
  {
    GDescs gd;
    gd.nd = 4;
    gd.d[0] = { sp_h, sp_l, wmtT_h, wmtT_l, b_mt, V[0],               64,  768,  0 };
    gd.d[1] = { mi_h, mi_l, wmiT_h, wmiT_l, b_mi, V[0] + 64 * DIMD,   64,  2048, 1 };
    gd.d[2] = { en_h, en_l, wetT_h, wetT_l, b_et, V[0] + 128 * DIMD,  1024, 768, 2 };
    gd.d[3] = { ei_h, ei_l, weiT_h, weiT_l, b_ei, V[0] + 1152 * DIMD, 1024, 2048, 10 };
    k_gemm_mfma<<<dim3(18, 6), 256, 0, stream>>>(gd);
  }

  // ---------------- GCN layers ----------------
  int cur = 0;
  for (int l = 0; l < 2; ++l) {
    int nxt = cur ^ 1;
    k_agg_m<<<DIMB, 256, 0, stream>>>(V[cur], ebuf[cur], SCAT);
    k_agg_e<<<(1024 * DIMD) / 256, 256, 0, stream>>>(V[cur], ebuf[cur], SCAT);
    {
      ADescs ad;
      ad.nd = 2;
      ad.d[0] = { SCAT,   sc_h, sc_l };
      ad.d[1] = { V[cur], vv_h, vv_l };
      ad.cum[0] = 0;
      ad.cum[1] = (int)(NV * 768 / 4);
      ad.cum[2] = (int)(2 * NV * 768 / 4);
      k_asplit<<<(ad.cum[2] + 255) / 256, 256, 0, stream>>>(ad);
    }
    {
      GDescs gd;
      gd.nd = 3;
      gd.d[0] = { sc_h, sc_l, whT_h[l], whT_l[l], wh_b + l * DIMD, V[nxt], (int)NV, 768, 0 };
      gd.d[1] = { vv_h, vv_l, wuT_h[l], wuT_l[l], wu_b + l * DIMD, FU, 128, 768, 17 };
      gd.d[2] = { vv_h + 128 * 768, vv_l + 128 * 768, wvT_h[l], wvT_l[l],
                  wv_b + l * DIMD, FV, 2048, 768, 18 };
      k_gemm_mfma<<<dim3(34, 6), 256, 0, stream>>>(gd);
    }
    k_ln_relu<<<(int)NV, 256, 0, stream>>>(V[nxt], ln_g + l * DIMD, ln_b + l * DIMD);
    k_edge_upd<<<BC, 256, 0, stream>>>(FU, FV, ebuf[cur], ebuf[nxt]);
    cur = nxt;
  }

  // ---------------- output ----------------
  k_out<<<BC, 256, 0, stream>>>(V[cur], out);
}

// Round 5
// 1090.237 us; speedup vs baseline: 1.8488x; 1.0460x over previous
//
#include <hip/hip_runtime.h>

#define DIMB 64
#define DIMC 16
#define DIMLM 40
#define DIMLE 32
#define DIMD 768
#define DIMR 2048
#define DIMP 49
#define BC (DIMB * DIMC)
#define NV 2176   // [v0(64); v1(64); v2(1024); v3(1024)]

typedef __attribute__((ext_vector_type(8))) short short8;
typedef __attribute__((ext_vector_type(4))) float f32x4;

// ---------------- reduction helpers ----------------
__device__ __forceinline__ float warpSum(float v) {
  v += __shfl_down(v, 32); v += __shfl_down(v, 16); v += __shfl_down(v, 8);
  v += __shfl_down(v, 4);  v += __shfl_down(v, 2);  v += __shfl_down(v, 1);
  return v;
}

__device__ __forceinline__ float blockSum256(float v, float* buf) {
  v = warpSum(v);
  int lane = threadIdx.x & 63, wid = threadIdx.x >> 6;
  if (lane == 0) buf[wid] = v;
  __syncthreads();
  float s = buf[0] + buf[1] + buf[2] + buf[3];
  __syncthreads();
  return s;
}

// split f32 -> bf16 hi (truncate) + bf16 lo (RNE of residual)
__device__ __forceinline__ void splitf(float x, unsigned short& h, unsigned short& l) {
  unsigned bx = __float_as_uint(x);
  h = (unsigned short)(bx >> 16);
  float lo = x - __uint_as_float(bx & 0xffff0000u);
  unsigned bl = __float_as_uint(lo);
  l = (unsigned short)((bl + 0x7fffu + ((bl >> 16) & 1u)) >> 16);
}

__device__ __forceinline__ void split4(float4 o, uint2& hp, uint2& lp) {
  unsigned short h0, h1, h2, h3, l0, l1, l2, l3;
  splitf(o.x, h0, l0); splitf(o.y, h1, l1);
  splitf(o.z, h2, l2); splitf(o.w, h3, l3);
  hp.x = (unsigned)h0 | ((unsigned)h1 << 16); hp.y = (unsigned)h2 | ((unsigned)h3 << 16);
  lp.x = (unsigned)l0 | ((unsigned)l1 << 16); lp.y = (unsigned)l2 | ((unsigned)l3 << 16);
}

// ---------------- span mean + split ----------------
__global__ void k_span_split(const float* __restrict__ mtf, const int* __restrict__ st,
                             const int* __restrict__ en, float* __restrict__ spanf,
                             unsigned short* __restrict__ H, unsigned short* __restrict__ L) {
  int b = blockIdx.x;
  int s = st[b], e = en[b];
  float cnt = 0.0f;
  for (int p = 0; p < DIMLM; ++p) cnt += (p >= s && p <= e) ? 1.0f : 0.0f;
  float rden = 1.0f / fmaxf(cnt, 1e-9f);
  for (int d4 = threadIdx.x; d4 < DIMD / 4; d4 += 256) {
    float4 a = {0.f, 0.f, 0.f, 0.f};
    for (int p = s; p <= e && p < DIMLM; ++p) {
      float4 v = ((const float4*)(mtf + ((size_t)b * DIMLM + p) * DIMD))[d4];
      a.x += v.x; a.y += v.y; a.z += v.z; a.w += v.w;
    }
    float4 o = { a.x * rden, a.y * rden, a.z * rden, a.w * rden };
    ((float4*)(spanf + (size_t)b * DIMD))[d4] = o;
    uint2 hp, lp; split4(o, hp, lp);
    ((uint2*)H)[(size_t)b * (DIMD / 4) + d4] = hp;
    ((uint2*)L)[(size_t)b * (DIMD / 4) + d4] = lp;
  }
}

// ---------------- entity text masked mean + split ----------------
__global__ void k_entrep_split(const float* __restrict__ etf, const int* __restrict__ etm,
                               unsigned short* __restrict__ H, unsigned short* __restrict__ L) {
  int bc = blockIdx.x;
  const float4* f = (const float4*)(etf + (size_t)bc * DIMLE * DIMD);
  const int* mk = etm + bc * DIMLE;
  float cnt = 0.0f;
  for (int l = 0; l < DIMLE; ++l) cnt += (float)mk[l];
  float rden = 1.0f / fmaxf(cnt, 1e-9f);
  for (int d4 = threadIdx.x; d4 < DIMD / 4; d4 += 256) {
    float sx = 0, sy = 0, sz = 0, sw = 0;
    for (int l = 0; l < DIMLE; ++l) {
      float m = (float)mk[l];
      float4 v = f[(size_t)l * (DIMD / 4) + d4];
      sx += v.x * m; sy += v.y * m; sz += v.z * m; sw += v.w * m;
    }
    float4 o = { sx * rden, sy * rden, sz * rden, sw * rden };
    uint2 hp, lp; split4(o, hp, lp);
    ((uint2*)H)[(size_t)bc * (DIMD / 4) + d4] = hp;
    ((uint2*)L)[(size_t)bc * (DIMD / 4) + d4] = lp;
  }
}

// ---------------- mean over P + split (mif rows 0..63, eif rows 64..1087) ----------------
__global__ void k_pmean_split(const float* __restrict__ mif, const float* __restrict__ eif,
                              unsigned short* __restrict__ mi_h, unsigned short* __restrict__ mi_l,
                              unsigned short* __restrict__ ei_h, unsigned short* __restrict__ ei_l) {
  int row = blockIdx.y;
  int r4 = blockIdx.x * 256 + threadIdx.x;   // 0..511
  const float* src; unsigned short *H, *L; int lr;
  if (row < DIMB) { src = mif; H = mi_h; L = mi_l; lr = row; }
  else            { src = eif; H = ei_h; L = ei_l; lr = row - DIMB; }
  const float4* p = (const float4*)(src + (size_t)lr * DIMP * DIMR) + r4;
  float sx = 0, sy = 0, sz = 0, sw = 0;
  for (int i = 0; i < DIMP; ++i) {
    float4 v = p[(size_t)i * (DIMR / 4)];
    sx += v.x; sy += v.y; sz += v.z; sw += v.w;
  }
  const float rn = 1.0f / (float)DIMP;
  float4 o = { sx * rn, sy * rn, sz * rn, sw * rn };
  uint2 hp, lp; split4(o, hp, lp);
  ((uint2*)H)[(size_t)lr * (DIMR / 4) + r4] = hp;
  ((uint2*)L)[(size_t)lr * (DIMR / 4) + r4] = lp;
}

// ---------------- cos(span, etf[:,:,0]) + edge1/2 init ----------------
__global__ void k_mtet(const float* __restrict__ span, const float* __restrict__ etf,
                       const float* __restrict__ mtei, const float* __restrict__ miet,
                       float* __restrict__ e0, float* __restrict__ e1,
                       float* __restrict__ e2) {
  __shared__ float buf[4];
  int bc = blockIdx.x, b = bc >> 4;
  const float* x = span + b * DIMD;
  const float* y = etf + (size_t)bc * DIMLE * DIMD;
  float dot = 0, nx = 0, ny = 0;
  for (int d = threadIdx.x; d < DIMD; d += 256) {
    float xv = x[d], yv = y[d];
    dot += xv * yv; nx += xv * xv; ny += yv * yv;
  }
  dot = blockSum256(dot, buf);
  nx = blockSum256(nx, buf);
  ny = blockSum256(ny, buf);
  if (threadIdx.x == 0) e0[bc] = dot / fmaxf(sqrtf(nx) * sqrtf(ny), 1e-8f);
  if (threadIdx.x == 1) e1[bc] = mtei[bc] * 0.01f;
  if (threadIdx.x == 2) e2[bc] = miet[bc] * 0.01f;
}

// ---------------- object pairwise cosine ----------------
__global__ void k_miei(const float* __restrict__ mof, const float* __restrict__ eof,
                       const float* __restrict__ mos, const float* __restrict__ eos,
                       float* __restrict__ e3) {
  __shared__ float red[24][4];
  int bc = blockIdx.x, b = bc >> 4;
  const float* mop = mof + (size_t)b * 4 * DIMR;
  const float* eop = eof + (size_t)bc * 4 * DIMR;
  float dots[16] = {}; float nm2[4] = {}; float ne2[4] = {};
  for (int r = threadIdx.x; r < DIMR; r += 256) {
    float mv[4], ev[4];
#pragma unroll
    for (int m = 0; m < 4; ++m) mv[m] = mop[(size_t)m * DIMR + r];
#pragma unroll
    for (int n = 0; n < 4; ++n) ev[n] = eop[(size_t)n * DIMR + r];
#pragma unroll
    for (int m = 0; m < 4; ++m) {
      nm2[m] += mv[m] * mv[m];
#pragma unroll
      for (int n = 0; n < 4; ++n) dots[m * 4 + n] += mv[m] * ev[n];
    }
#pragma unroll
    for (int n = 0; n < 4; ++n) ne2[n] += ev[n] * ev[n];
  }
  int lane = threadIdx.x & 63, wid = threadIdx.x >> 6;
#pragma unroll
  for (int i = 0; i < 24; ++i) {
    float v = (i < 16) ? dots[i] : (i < 20 ? nm2[i - 16] : ne2[i - 20]);
    v = warpSum(v);
    if (lane == 0) red[i][wid] = v;
  }
  __syncthreads();
  if (threadIdx.x == 0) {
    float dsum[16], nmv[4], nev[4];
    for (int i = 0; i < 16; ++i) dsum[i] = red[i][0] + red[i][1] + red[i][2] + red[i][3];
    for (int m = 0; m < 4; ++m)
      nmv[m] = sqrtf(red[16 + m][0] + red[16 + m][1] + red[16 + m][2] + red[16 + m][3]);
    for (int n = 0; n < 4; ++n)
      nev[n] = sqrtf(red[20 + n][0] + red[20 + n][1] + red[20 + n][2] + red[20 + n][3]);
    float num = 0, den = 0;
    for (int m = 0; m < 4; ++m)
      for (int n = 0; n < 4; ++n) {
        float sim = dsum[m * 4 + n] / fmaxf(nmv[m] * nev[n], 1e-8f);
        float sc = mos[b * 4 + m] * eos[bc * 4 + n];
        num += sim * sc; den += sc;
      }
    e3[bc] = num / (den + 1e-9f);
  }
}

// ---------------- weight transpose + split ----------------
struct WDesc { const float* W; unsigned short* Th; unsigned short* Tl; int K; };
struct WDescs { WDesc d[10]; };
__global__ void k_wsplitT(WDescs wd) {
  const WDesc D = wd.d[blockIdx.z];
  int kb = blockIdx.x * 32;
  if (kb >= D.K) return;
  int nb = blockIdx.y * 32;
  __shared__ float t[32][33];
  int c = threadIdx.x & 31, r8 = threadIdx.x >> 5;
#pragma unroll
  for (int i = 0; i < 4; ++i) {
    int kk = r8 + i * 8;
    t[kk][c] = D.W[(size_t)(kb + kk) * DIMD + nb + c];
  }
  __syncthreads();
#pragma unroll
  for (int i = 0; i < 4; ++i) {
    int nn = r8 + i * 8;
    unsigned short h, l;
    splitf(t[c][nn], h, l);
    size_t o = (size_t)(nb + nn) * D.K + kb + c;
    D.Th[o] = h; D.Tl[o] = l;
  }
}

// ---------------- split-bf16 MFMA GEMM, batched descriptors ----------------
#define BMg 128
#define BNg 128
#define BKg 32
#define LDP 40
struct GDesc {
  const unsigned short *Ah, *Al, *Wh, *Wl;
  const float* bias; float* C; int M, K, mb0;
};
struct GDescs { GDesc d[4]; int nd; };

__global__ __launch_bounds__(256) void k_gemm_mfma(GDescs gd) {
  int bx = blockIdx.x;
  int z = 0;
  while (z + 1 < gd.nd && bx >= gd.d[z + 1].mb0) ++z;
  const GDesc D = gd.d[z];
  const int m0 = (bx - D.mb0) * BMg;
  const int n0 = blockIdx.y * BNg;
  const int K = D.K, M = D.M;

  __shared__ unsigned short sAh[2][BMg * LDP];
  __shared__ unsigned short sAl[2][BMg * LDP];
  __shared__ unsigned short sWh[2][BMg * LDP];
  __shared__ unsigned short sWl[2][BMg * LDP];

  const int tid = threadIdx.x;
  uint4 st[8];

  auto issue = [&](int kt) {
    int k0 = kt * BKg;
#pragma unroll
    for (int i = 0; i < 8; ++i) {
      int u = tid + (i & 1) * 256;
      int r = u >> 2, q = u & 3;
      const unsigned short* src;
      int row;
      if (i < 4) { row = m0 + r; if (row >= M) row = M - 1; src = (i < 2) ? D.Ah : D.Al; }
      else       { row = n0 + r;                            src = (i < 6) ? D.Wh : D.Wl; }
      st[i] = *(const uint4*)(src + (size_t)row * K + k0 + q * 8);
    }
  };
  auto commit = [&](int b) {
#pragma unroll
    for (int i = 0; i < 8; ++i) {
      int u = tid + (i & 1) * 256;
      int r = u >> 2, q = u & 3;
      unsigned short* dst = (i < 2) ? sAh[b] : (i < 4) ? sAl[b] : (i < 6) ? sWh[b] : sWl[b];
      *(uint4*)(dst + r * LDP + q * 8) = st[i];
    }
  };

  f32x4 acc[4][4];
#pragma unroll
  for (int i = 0; i < 4; ++i)
#pragma unroll
    for (int j = 0; j < 4; ++j) acc[i][j] = (f32x4){0.f, 0.f, 0.f, 0.f};

  const int lane = tid & 63, w = tid >> 6;
  const int wr = (w >> 1) * 64, wc = (w & 1) * 64;
  const int fr = lane & 15, fg = lane >> 4;

  issue(0); commit(0); __syncthreads();
  const int nt = K / BKg;
  for (int t = 0; t < nt; ++t) {
    int b = t & 1;
    if (t + 1 < nt) issue(t + 1);
    short8 ah[4], al[4];
#pragma unroll
    for (int mi = 0; mi < 4; ++mi) {
      int ro = (wr + mi * 16 + fr) * LDP + fg * 8;
      ah[mi] = *(const short8*)(sAh[b] + ro);
      al[mi] = *(const short8*)(sAl[b] + ro);
    }
#pragma unroll
    for (int ni = 0; ni < 4; ++ni) {
      int co = (wc + ni * 16 + fr) * LDP + fg * 8;
      short8 wh8 = *(const short8*)(sWh[b] + co);
      short8 wl8 = *(const short8*)(sWl[b] + co);
#pragma unroll
      for (int mi = 0; mi < 4; ++mi) {
        acc[mi][ni] = __builtin_amdgcn_mfma_f32_16x16x32_bf16(ah[mi], wh8, acc[mi][ni], 0, 0, 0);
        acc[mi][ni] = __builtin_amdgcn_mfma_f32_16x16x32_bf16(ah[mi], wl8, acc[mi][ni], 0, 0, 0);
        acc[mi][ni] = __builtin_amdgcn_mfma_f32_16x16x32_bf16(al[mi], wh8, acc[mi][ni], 0, 0, 0);
      }
    }
    if (t + 1 < nt) commit((t + 1) & 1);
    __syncthreads();
  }

#pragma unroll
  for (int mi = 0; mi < 4; ++mi) {
#pragma unroll
    for (int r = 0; r < 4; ++r) {
      int grow = m0 + wr + mi * 16 + fg * 4 + r;
      if (grow < M) {
#pragma unroll
        for (int ni = 0; ni < 4; ++ni) {
          int gcol = n0 + wc + ni * 16 + fr;
          D.C[(size_t)grow * DIMD + gcol] = acc[mi][ni][r] + D.bias[gcol];
        }
      }
    }
  }
}

// ---------------- fused layer-pre: aggregate + split sc, split vv ----------------
__global__ void k_layer_pre(const float* __restrict__ V, const float* __restrict__ e,
                            unsigned short* __restrict__ sc_h, unsigned short* __restrict__ sc_l,
                            unsigned short* __restrict__ vv_h, unsigned short* __restrict__ vv_l) {
  size_t i4 = (size_t)blockIdx.x * 256 + threadIdx.x;    // over NV*192
  int row = (int)(i4 / (DIMD / 4)), d4 = (int)(i4 % (DIMD / 4));
  const float4* v0 = (const float4*)V;
  const float4* v1 = v0 + (size_t)64 * (DIMD / 4);
  const float4* v2 = v0 + (size_t)128 * (DIMD / 4);
  const float4* v3 = v0 + (size_t)1152 * (DIMD / 4);

  // vv = split of V itself
  float4 vself = ((const float4*)V)[i4];
  uint2 hp, lp; split4(vself, hp, lp);
  ((uint2*)vv_h)[i4] = hp;
  ((uint2*)vv_l)[i4] = lp;

  float4 s;
  if (row < 128) {
    int b = row & 63;
    int men = row >> 6;  // 0: v0 (edges 0,1), 1: v1 (edges 2,3)
    const float* ea = e + (men ? 2 * BC : 0);
    const float* eb_ = e + (men ? 3 * BC : BC);
    float ax = 0, ay = 0, az = 0, aw = 0;
    for (int c = 0; c < DIMC; ++c) {
      int bc = b * DIMC + c;
      float4 x2 = v2[(size_t)bc * (DIMD / 4) + d4];
      float4 x3 = v3[(size_t)bc * (DIMD / 4) + d4];
      float w2 = ea[bc], w3 = eb_[bc];
      ax += w2 * x2.x + w3 * x3.x; ay += w2 * x2.y + w3 * x3.y;
      az += w2 * x2.z + w3 * x3.z; aw += w2 * x2.w + w3 * x3.w;
    }
    float4 u = (men ? v1 : v0)[(size_t)b * (DIMD / 4) + d4];
    const float inv = 1.0f / DIMC;
    s.x = u.x + ax * inv; s.y = u.y + ay * inv;
    s.z = u.z + az * inv; s.w = u.w + aw * inv;
  } else {
    int ent = (row >= 1152);                 // 0: v2 (edges 0,2), 1: v3 (edges 1,3)
    int bc = row - (ent ? 1152 : 128);
    int b = bc >> 4;
    float w0 = e[bc + (ent ? BC : 0)];
    float w1 = e[bc + (ent ? 3 * BC : 2 * BC)];
    float4 x0 = v0[(size_t)b * (DIMD / 4) + d4];
    float4 x1 = v1[(size_t)b * (DIMD / 4) + d4];
    float4 u = (ent ? v3 : v2)[(size_t)bc * (DIMD / 4) + d4];
    s.x = u.x + w0 * x0.x + w1 * x1.x; s.y = u.y + w0 * x0.y + w1 * x1.y;
    s.z = u.z + w0 * x0.z + w1 * x1.z; s.w = u.w + w0 * x0.w + w1 * x1.w;
  }
  split4(s, hp, lp);
  ((uint2*)sc_h)[i4] = hp;
  ((uint2*)sc_l)[i4] = lp;
}

// ---------------- LayerNorm + ReLU ----------------
__global__ void k_ln_relu(float* __restrict__ x, const float* __restrict__ g,
                          const float* __restrict__ bb) {
  __shared__ float buf[4];
  float* xr = x + (size_t)blockIdx.x * DIMD;
  float v[3];
  float s = 0.0f;
#pragma unroll
  for (int i = 0; i < 3; ++i) { v[i] = xr[threadIdx.x + i * 256]; s += v[i]; }
  float mu = blockSum256(s, buf) / (float)DIMD;
  float q = 0.0f;
#pragma unroll
  for (int i = 0; i < 3; ++i) { float d = v[i] - mu; q += d * d; }
  float var = blockSum256(q, buf) / (float)DIMD;
  float inv = 1.0f / sqrtf(var + 1e-5f);
#pragma unroll
  for (int i = 0; i < 3; ++i) {
    int d = threadIdx.x + i * 256;
    float y = (v[i] - mu) * inv * g[d] + bb[d];
    xr[d] = fmaxf(y, 0.0f);
  }
}

// ---------------- edge update ----------------
__global__ void k_edge_upd(const float* __restrict__ FU, const float* __restrict__ FV,
                           const float* __restrict__ eold, float* __restrict__ enew) {
  __shared__ float buf[4];
  int bc = blockIdx.x, b = bc >> 4;
  const float* fu0 = FU;
  const float* fu1 = FU + 64 * DIMD;
  const float* fv2 = FV;
  const float* fv3 = FV + (size_t)1024 * DIMD;
  float d02 = 0, d03 = 0, d12 = 0, d13 = 0;
  for (int d = threadIdx.x; d < DIMD; d += 256) {
    float u0 = fu0[b * DIMD + d], u1 = fu1[b * DIMD + d];
    float w2 = fv2[(size_t)bc * DIMD + d], w3 = fv3[(size_t)bc * DIMD + d];
    d02 += u0 * w2; d03 += u0 * w3; d12 += u1 * w2; d13 += u1 * w3;
  }
  d02 = blockSum256(d02, buf);
  d03 = blockSum256(d03, buf);
  d12 = blockSum256(d12, buf);
  d13 = blockSum256(d13, buf);
  if (threadIdx.x == 0) {
    enew[bc]          = fmaxf(d02 / (float)DIMD + eold[bc], 0.0f);
    enew[BC + bc]     = fmaxf(d03 / (float)DIMD + eold[BC + bc], 0.0f);
    enew[2 * BC + bc] = fmaxf(d12 / (float)DIMD + eold[2 * BC + bc], 0.0f);
    enew[3 * BC + bc] = fmaxf(d13 / (float)DIMD + eold[3 * BC + bc], 0.0f);
  }
}

// ---------------- final cosine ----------------
__global__ void k_out(const float* __restrict__ V, float* __restrict__ outp) {
  __shared__ float buf[4];
  int bc = blockIdx.x, b = bc >> 4;
  const float* nv0 = V;
  const float* nv2 = V + 128 * DIMD;
  float dot = 0, n0 = 0, n2 = 0;
  for (int d = threadIdx.x; d < DIMD; d += 256) {
    float x = nv0[b * DIMD + d], y = nv2[(size_t)bc * DIMD + d];
    dot += x * y; n0 += x * x; n2 += y * y;
  }
  dot = blockSum256(dot, buf);
  n0 = blockSum256(n0, buf);
  n2 = blockSum256(n2, buf);
  if (threadIdx.x == 0) outp[bc] = dot / fmaxf(sqrtf(n0) * sqrtf(n2), 1e-8f);
}

extern "C" void kernel_launch(void* const* d_in, const int* in_sizes, int n_in,
                              void* d_out, int out_size, void* d_ws, size_t ws_size,
                              hipStream_t stream) {
  const float* mtf    = (const float*)d_in[0];
  const int*   mstart = (const int*)d_in[2];
  const int*   mend   = (const int*)d_in[3];
  const float* mif  = (const float*)d_in[4];
  const float* mof  = (const float*)d_in[5];
  const float* mos  = (const float*)d_in[6];
  const float* etf  = (const float*)d_in[7];
  const int*   etm  = (const int*)d_in[8];
  const float* eif  = (const float*)d_in[9];
  const float* eof  = (const float*)d_in[10];
  const float* eos  = (const float*)d_in[11];
  const float* miet = (const float*)d_in[12];
  const float* mtei = (const float*)d_in[13];
  const float* w_mt = (const float*)d_in[14]; const float* b_mt = (const float*)d_in[15];
  const float* w_et = (const float*)d_in[16]; const float* b_et = (const float*)d_in[17];
  const float* w_mi = (const float*)d_in[18]; const float* b_mi = (const float*)d_in[19];
  const float* w_ei = (const float*)d_in[20]; const float* b_ei = (const float*)d_in[21];
  const float* wh_w = (const float*)d_in[22]; const float* wh_b = (const float*)d_in[23];
  const float* wu_w = (const float*)d_in[24]; const float* wu_b = (const float*)d_in[25];
  const float* wv_w = (const float*)d_in[26]; const float* wv_b = (const float*)d_in[27];
  const float* ln_g = (const float*)d_in[28]; const float* ln_b = (const float*)d_in[29];
  float* out = (float*)d_out;

  float* ws = (float*)d_ws;
  size_t off = 0;
  auto alloc = [&](size_t n) { float* p = ws + off; off += n; return p; };
  float* span  = alloc((size_t)DIMB * DIMD);
  float* V[2]  = { alloc((size_t)NV * DIMD), alloc((size_t)NV * DIMD) };
  float* FU    = alloc((size_t)128 * DIMD);
  float* FV    = alloc((size_t)2048 * DIMD);
  float* ebuf[2] = { alloc((size_t)4 * BC), alloc((size_t)4 * BC) };

  unsigned short* us = (unsigned short*)(ws + off);
  size_t uoff = 0;
  auto ualloc = [&](size_t n) { unsigned short* p = us + uoff; uoff += n; return p; };
  unsigned short* sp_h = ualloc(64 * 768);   unsigned short* sp_l = ualloc(64 * 768);
  unsigned short* mi_h = ualloc(64 * 2048);  unsigned short* mi_l = ualloc(64 * 2048);
  unsigned short* en_h = ualloc(1024 * 768); unsigned short* en_l = ualloc(1024 * 768);
  unsigned short* ei_h = ualloc((size_t)1024 * 2048); unsigned short* ei_l = ualloc((size_t)1024 * 2048);
  unsigned short* sc_h = ualloc((size_t)NV * 768);   unsigned short* sc_l = ualloc((size_t)NV * 768);
  unsigned short* vv_h = ualloc((size_t)NV * 768);   unsigned short* vv_l = ualloc((size_t)NV * 768);
  unsigned short* wmtT_h = ualloc(768 * 768);  unsigned short* wmtT_l = ualloc(768 * 768);
  unsigned short* wetT_h = ualloc(768 * 768);  unsigned short* wetT_l = ualloc(768 * 768);
  unsigned short* wmiT_h = ualloc((size_t)768 * 2048); unsigned short* wmiT_l = ualloc((size_t)768 * 2048);
  unsigned short* weiT_h = ualloc((size_t)768 * 2048); unsigned short* weiT_l = ualloc((size_t)768 * 2048);
  unsigned short* whT_h[2] = { ualloc(768 * 768), ualloc(768 * 768) };
  unsigned short* whT_l[2] = { ualloc(768 * 768), ualloc(768 * 768) };
  unsigned short* wuT_h[2] = { ualloc(768 * 768), ualloc(768 * 768) };
  unsigned short* wuT_l[2] = { ualloc(768 * 768), ualloc(768 * 768) };
  unsigned short* wvT_h[2] = { ualloc(768 * 768), ualloc(768 * 768) };
  unsigned short* wvT_l[2] = { ualloc(768 * 768), ualloc(768 * 768) };

  // ---- stage 1: producers (fused reduce+split) + edges ----
  k_span_split<<<DIMB, 256, 0, stream>>>(mtf, mstart, mend, span, sp_h, sp_l);
  k_entrep_split<<<BC, 256, 0, stream>>>(etf, etm, en_h, en_l);
  k_pmean_split<<<dim3(2, DIMB + BC), 256, 0, stream>>>(mif, eif, mi_h, mi_l, ei_h, ei_l);
  k_mtet<<<BC, 256, 0, stream>>>(span, etf, mtei, miet,
                                 ebuf[0], ebuf[0] + BC, ebuf[0] + 2 * BC);
  k_miei<<<BC, 256, 0, stream>>>(mof, eof, mos, eos, ebuf[0] + 3 * BC);

  // ---- stage 2: weight transpose+split ----
  {
    WDescs wd;
    wd.d[0] = { w_mt, wmtT_h, wmtT_l, 768 };
    wd.d[1] = { w_et, wetT_h, wetT_l, 768 };
    wd.d[2] = { w_mi, wmiT_h, wmiT_l, 2048 };
    wd.d[3] = { w_ei, weiT_h, weiT_l, 2048 };
    wd.d[4] = { wh_w,             whT_h[0], whT_l[0], 768 };
    wd.d[5] = { wh_w + 768 * 768, whT_h[1], whT_l[1], 768 };
    wd.d[6] = { wu_w,             wuT_h[0], wuT_l[0], 768 };
    wd.d[7] = { wu_w + 768 * 768, wuT_h[1], wuT_l[1], 768 };
    wd.d[8] = { wv_w,             wvT_h[0], wvT_l[0], 768 };
    wd.d[9] = { wv_w + 768 * 768, wvT_h[1], wvT_l[1], 768 };
    k_wsplitT<<<dim3(2048 / 32, 768 / 32, 10), 256, 0, stream>>>(wd);
  }

  // ---- stage 3: projection GEMMs ----
  {
    GDescs gd;
    gd.nd = 4;
    gd.d[0] = { sp_h, sp_l, wmtT_h, wmtT_l, b_mt, V[0],               64,   768,  0 };
    gd.d[1] = { mi_h, mi_l, wmiT_h, wmiT_l, b_mi, V[0] + 64 * DIMD,   64,   2048, 1 };
    gd.d[2] = { en_h, en_l, wetT_h, wetT_l, b_et, V[0] + 128 * DIMD,  1024, 768,  2 };
    gd.d[3] = { ei_h, ei_l, weiT_h, weiT_l, b_ei, V[0] + 1152 * DIMD, 1024, 2048, 10 };
    k_gemm_mfma<<<dim3(18, 6), 256, 0, stream>>>(gd);
  }

  // ---- GCN layers ----
  int cur = 0;
  for (int l = 0; l < 2; ++l) {
    int nxt = cur ^ 1;
    k_layer_pre<<<(NV * DIMD / 4) / 256, 256, 0, stream>>>(V[cur], ebuf[cur],
                                                           sc_h, sc_l, vv_h, vv_l);
    {
      GDescs gd;
      gd.nd = 3;
      gd.d[0] = { sc_h, sc_l, whT_h[l], whT_l[l], wh_b + l * DIMD, V[nxt], NV, 768, 0 };
      gd.d[1] = { vv_h, vv_l, wuT_h[l], wuT_l[l], wu_b + l * DIMD, FU, 128, 768, 17 };
      gd.d[2] = { vv_h + (size_t)128 * 768, vv_l + (size_t)128 * 768, wvT_h[l], wvT_l[l],
                  wv_b + l * DIMD, FV, 2048, 768, 18 };
      k_gemm_mfma<<<dim3(34, 6), 256, 0, stream>>>(gd);
    }
    k_ln_relu<<<NV, 256, 0, stream>>>(V[nxt], ln_g + l * DIMD, ln_b + l * DIMD);
    k_edge_upd<<<BC, 256, 0, stream>>>(FU, FV, ebuf[cur], ebuf[nxt]);
    cur = nxt;
  }

  // ---- output ----
  k_out<<<BC, 256, 0, stream>>>(V[cur], out);
}